// Round 7
// baseline (96.232 us; speedup 1.0000x reference)
//
#include <hip/hip_runtime.h>
#include <hip/hip_bf16.h>

#define BATCH 16
#define CIN   128
#define HIMG  56
#define WIMG  56
#define NPIX  (HIMG*WIMG)      // 3136
#define CS    256
#define NQ    4
#define HOUT  28
#define WOUT  28
#define NOPIX (HOUT*WOUT)      // 784
#define QSCALE 0.17677669529663687f   // hc^-0.5 = 1/sqrt(32)
#define NCOL  288              // 256 V cols + 32 qk cols

typedef __attribute__((ext_vector_type(8))) short    bf16x8;
typedef __attribute__((ext_vector_type(4))) float    f32x4;
typedef __attribute__((ext_vector_type(4))) unsigned u32x4;

static __device__ __forceinline__ unsigned short f2bf(float f) {
    return __builtin_bit_cast(unsigned short, __float2bfloat16(f));
}
static __device__ __forceinline__ float bf2f(unsigned short u) {
    return __builtin_bit_cast(float, (unsigned)u << 16);
}
static __device__ __forceinline__ unsigned int pack2(float a, float b) {
    return (unsigned)f2bf(a) | ((unsigned)f2bf(b) << 16);
}

// ---------- kernel W: all weight prep, parallel ----------
// blocks 0..7  : Wout -> WoutHi/WoutLo bf16 split (hi + residual)
// blocks 8..15 : W' rows 0..255 (WvT repack, bf16, LINEAR — k1 reads from L2 now)
// block  16    : W' rows 256..287 (Wq' = q-folded Wk, bf16, linear)
__global__ __launch_bounds__(256) void kW_prep(
    const float* __restrict__ Wout, const float* __restrict__ Wk,
    const float* __restrict__ Wv,   const float* __restrict__ qp,
    unsigned short* __restrict__ WHi, unsigned short* __restrict__ WLo,
    unsigned short* __restrict__ Wp)
{
    __shared__ float buf[4352];   // 17 KB, aliased per block role
    const int t   = threadIdx.x;
    const int blk = blockIdx.x;
    char* wp = (char*)Wp;

    if (blk < 8) {
        // ---- Wout hi/lo split, coalesced ----
        const size_t base = (size_t)blk * 8192 + t;
        #pragma unroll
        for (int i = 0; i < 32; ++i) {
            const float f = Wout[base + i*256];
            const unsigned short h = f2bf(f);
            WHi[base + i*256] = h;
            WLo[base + i*256] = f2bf(f - bf2f(h));
        }
    } else if (blk < 16) {
        // ---- WvT repack: W' row ch holds Wv[*, ch] as bf16 pairs ----
        float (*lt)[33] = (float(*)[33])buf;           // 128*33 = 4224
        const int ch0 = (blk - 8) * 32;
        const int j = t & 31, r = t >> 5;              // r = 0..7
        #pragma unroll
        for (int pass = 0; pass < 16; ++pass) {
            const int c = r + pass*8;
            lt[c][j] = Wv[(size_t)c*CS + ch0 + j];     // coalesced 128B/row
        }
        __syncthreads();
        const int lch = t >> 3, sub = t & 7;
        const int ch  = ch0 + lch;
        #pragma unroll
        for (int i = 0; i < 8; ++i) {
            const int c2 = sub*8 + i;
            const unsigned u = pack2(lt[2*c2][lch], lt[2*c2+1][lch]);
            *(unsigned*)(wp + ch*256 + c2*4) = u;
        }
    } else {
        // ---- Wq'[qh][c] = sum_j Wk[c][h*32+j] * q[q][h*32+j] * QSCALE ----
        float* qs = buf;                               // 1024 floats
        for (int i = t; i < NQ*CS; i += 256) qs[i] = qp[i] * QSCALE;
        __syncthreads();
        const int qh = t >> 3, kg = t & 7;             // 32 rows x 8 k-groups
        const int h = qh & 7, q = qh >> 3;
        const int row = 256 + qh;
        const float* qv = &qs[q*CS + h*32];
        #pragma unroll
        for (int i = 0; i < 8; ++i) {
            const int c2 = kg*8 + i;
            float d0 = 0.f, d1 = 0.f;
            const float* wk0 = Wk + (size_t)(2*c2)*CS + h*32;
            const float* wk1 = wk0 + CS;
            #pragma unroll
            for (int j4 = 0; j4 < 32; j4 += 4) {
                const float4 a0 = *(const float4*)(wk0 + j4);
                const float4 a1 = *(const float4*)(wk1 + j4);
                const float4 qq = *(const float4*)(qv + j4);
                d0 = fmaf(a0.x, qq.x, d0); d0 = fmaf(a0.y, qq.y, d0);
                d0 = fmaf(a0.z, qq.z, d0); d0 = fmaf(a0.w, qq.w, d0);
                d1 = fmaf(a1.x, qq.x, d1); d1 = fmaf(a1.y, qq.y, d1);
                d1 = fmaf(a1.z, qq.z, d1); d1 = fmaf(a1.w, qq.w, d1);
            }
            *(unsigned*)(wp + row*256 + c2*4) = pack2(d0, d1);
        }
    }
}

// ---------- kernel 1: fused transpose+GEMM: x(f32, B,C,N) @ W'(128x288) ----------
// No LDS, no barrier. A-frags straight from x (16-lane 64B coalesced dwords,
// packed to bf16 in registers). B-frags straight from Wp via L1/L2: frag
// (n,s) = 16 rows x 64B contiguous sectors; per-s working set 18.4 KB (L1-fits).
__global__ __launch_bounds__(256, 3) void k1_mfma(
    const float* __restrict__ x, const unsigned short* __restrict__ Wp,
    float* __restrict__ costO, unsigned short* __restrict__ Vout)
{
    const int t    = threadIdx.x;
    const int lane = t & 63;
    const int w    = t >> 6;
    const int l15  = lane & 15;
    const int hi   = lane >> 4;
    const int gp0  = blockIdx.x * 64;           // 64-pixel tile, never crosses batch
    const int b    = gp0 / NPIX;
    const int p    = gp0 - b*NPIX + w*16 + l15;

    // issue A loads (32 dwords, 16-lane coalesced into 64B sectors)
    float av[4][8];
    {
        const float* xb = x + (size_t)b*CIN*NPIX + (size_t)(hi*8)*NPIX + p;
        #pragma unroll
        for (int s = 0; s < 4; ++s)
            #pragma unroll
            for (int j = 0; j < 8; ++j)
                av[s][j] = xb[(size_t)(s*32 + j)*NPIX];
    }

    // pack A to bf16 frags
    bf16x8 afr[4];
    #pragma unroll
    for (int s = 0; s < 4; ++s) {
        u32x4 u;
        u[0] = pack2(av[s][0], av[s][1]);
        u[1] = pack2(av[s][2], av[s][3]);
        u[2] = pack2(av[s][4], av[s][5]);
        u[3] = pack2(av[s][6], av[s][7]);
        afr[s] = __builtin_bit_cast(bf16x8, u);
    }

    f32x4 acc[18];
    #pragma unroll
    for (int n = 0; n < 18; ++n) acc[n] = (f32x4){0.f,0.f,0.f,0.f};

    // B-frag base: row (n*16 + l15), k-offset s*32 + hi*8 (elements)
    const unsigned short* bp = Wp + (size_t)l15*CIN + hi*8;

    #pragma unroll
    for (int s = 0; s < 4; ++s) {
        #pragma unroll
        for (int n = 0; n < 18; ++n) {
            const bf16x8 bfr = *(const bf16x8*)(bp + n*16*CIN + s*32);
            acc[n] = __builtin_amdgcn_mfma_f32_16x16x32_bf16(afr[s], bfr, acc[n], 0, 0, 0);
        }
    }

    const size_t prow0 = (size_t)gp0 + w*16 + hi*4;
    #pragma unroll
    for (int n = 0; n < 16; ++n) {          // V cols, bf16
        unsigned short* vp = Vout + prow0*CS + n*16 + l15;
        #pragma unroll
        for (int r = 0; r < 4; ++r)
            vp[(size_t)r*CS] = f2bf(acc[n][r]);
    }
    #pragma unroll
    for (int n = 16; n < 18; ++n) {         // qk cols -> cost = exp(qk)
        float* cp = costO + prow0*32 + (n-16)*16 + l15;
        #pragma unroll
        for (int r = 0; r < 4; ++r)
            cp[(size_t)r*32] = __expf(acc[n][r]);
    }
}

// ---------- kernel 2: 9-tap aggregation, 1 wave = 1 output pixel ----------
// XCD-swizzled block order: each XCD's L2 sees a contiguous ~2-batch V slice.
__global__ __launch_bounds__(256) void k2_agg(
    const float* __restrict__ cost, const unsigned short* __restrict__ V,
    const float* __restrict__ ascale, const float* __restrict__ rpb,
    unsigned short* __restrict__ pre)
{
    const int t    = threadIdx.x;
    const int lane = t & 63;
    const int w    = t >> 6;
    // bijective XCD swizzle: 3136 blocks, 3136/8 = 392 contiguous per XCD
    const int bid  = blockIdx.x;
    const int rb   = (bid & 7) * 392 + (bid >> 3);
    const int gp   = rb*4 + w;            // global out-pixel = b*784 + ho*28 + wo
    const int b    = gp / NOPIX;
    const int rem  = gp % NOPIX;
    const int ho   = rem / WOUT, wo = rem % WOUT;
    const int qh   = lane & 31;

    int pk[9];
    #pragma unroll
    for (int k = 0; k < 9; ++k) {
        const int y  = 2*ho - 1 + k/3;
        const int xx = 2*wo - 1 + k%3;
        const bool v = ((unsigned)y < (unsigned)HIMG) && ((unsigned)xx < (unsigned)WIMG);
        pk[k] = v ? (y*WIMG + xx) : -1;
    }

    // per-qh: den and cp[k]
    float cp[9];
    float den = 0.f;
    #pragma unroll
    for (int k = 0; k < 9; ++k) {
        const float s  = (pk[k] >= 0) ? cost[((size_t)(b*NPIX) + pk[k])*32 + qh] : 0.f;
        const float wd = __expf(rpb[k*32 + qh]);
        den   = fmaf(wd, s, den);
        cp[k] = wd * ascale[k*32 + qh] * s;
    }
    const float rden = 1.f / den;

    // coef[k][h] = sum_q cp[k][q*8+h]/den ; broadcast to lane's h = lane>>3
    float coef[9];
    #pragma unroll
    for (int k = 0; k < 9; ++k) {
        float v = cp[k] * rden;
        v += __shfl_xor(v, 8);
        v += __shfl_xor(v, 16);
        coef[k] = __shfl(v, lane >> 3);
    }

    // accumulate 4 channels (lane*4 .. +3)
    float a0 = 0.f, a1 = 0.f, a2 = 0.f, a3 = 0.f;
    #pragma unroll
    for (int k = 0; k < 9; ++k) {
        const int p = (pk[k] >= 0) ? pk[k] : 0;       // coef==0 for invalid taps
        const ushort4 v4 = *(const ushort4*)(V + ((size_t)(b*NPIX) + p)*CS + lane*4);
        a0 = fmaf(coef[k], bf2f(v4.x), a0);
        a1 = fmaf(coef[k], bf2f(v4.y), a1);
        a2 = fmaf(coef[k], bf2f(v4.z), a2);
        a3 = fmaf(coef[k], bf2f(v4.w), a3);
    }
    ushort4 o;
    o.x = f2bf(a0); o.y = f2bf(a1); o.z = f2bf(a2); o.w = f2bf(a3);
    *(ushort4*)(pre + (size_t)gp*CS + lane*4) = o;
}

// ---------- kernel 3: out = Wout @ pre^T via MFMA, hi/lo split A ----------
__global__ __launch_bounds__(256) void k3_mfma(
    const unsigned short* __restrict__ pre, const unsigned short* __restrict__ WHi,
    const unsigned short* __restrict__ WLo, float* __restrict__ out)
{
    const int t    = threadIdx.x;
    const int lane = t & 63;
    const int w    = t >> 6;
    const int l15  = lane & 15;
    const int hi   = lane >> 4;
    const int blk  = blockIdx.x;           // b*28 + otile*7 + ptile
    const int b    = blk / 28;
    const int rem  = blk % 28;
    const int o0   = (rem / 7) * 64 + w * 16;
    const int p0   = (rem % 7) * 112;

    bf16x8 aH[8], aL[8];
    {
        const unsigned short* ah = WHi + (size_t)(o0 + l15)*CS + hi*8;
        const unsigned short* al = WLo + (size_t)(o0 + l15)*CS + hi*8;
        #pragma unroll
        for (int s = 0; s < 8; ++s) {
            aH[s] = *(const bf16x8*)(ah + s*32);
            aL[s] = *(const bf16x8*)(al + s*32);
        }
    }

    const unsigned short* bbase = pre + ((size_t)(b*NOPIX) + p0 + l15)*CS + hi*8;

    f32x4 acc[7];
    #pragma unroll
    for (int n = 0; n < 7; ++n) acc[n] = (f32x4){0.f,0.f,0.f,0.f};

    #pragma unroll
    for (int n = 0; n < 7; ++n) {
        const unsigned short* bn = bbase + (size_t)(n*16)*CS;
        bf16x8 bf[8];
        #pragma unroll
        for (int s = 0; s < 8; ++s) bf[s] = *(const bf16x8*)(bn + s*32);
        #pragma unroll
        for (int s = 0; s < 8; ++s) {
            acc[n] = __builtin_amdgcn_mfma_f32_16x16x32_bf16(aH[s], bf[s], acc[n], 0, 0, 0);
            acc[n] = __builtin_amdgcn_mfma_f32_16x16x32_bf16(aL[s], bf[s], acc[n], 0, 0, 0);
        }
    }

    #pragma unroll
    for (int n = 0; n < 7; ++n) {
        #pragma unroll
        for (int r = 0; r < 4; ++r)
            out[((size_t)(b*CS) + o0 + hi*4 + r)*NOPIX + p0 + n*16 + l15] = acc[n][r];
    }
}

extern "C" void kernel_launch(void* const* d_in, const int* in_sizes, int n_in,
                              void* d_out, int out_size, void* d_ws, size_t ws_size,
                              hipStream_t stream) {
    const float* x      = (const float*)d_in[0];
    const float* Wk     = (const float*)d_in[1];
    const float* Wv     = (const float*)d_in[2];
    const float* Wout   = (const float*)d_in[3];
    const float* qp     = (const float*)d_in[4];
    const float* ascale = (const float*)d_in[5];
    const float* rpb    = (const float*)d_in[6];
    float* out = (float*)d_out;

    // ws layout (bytes):
    //   cost f32 : 6,422,528
    //   V bf16   : 25,690,112
    //   pre bf16 : 6,422,528
    //   WoutHi   : 131,072 | WoutLo: 131,072 | Wp: 73,728   -> ~38.9 MB
    char* ws = (char*)d_ws;
    float*          cost = (float*)(ws);
    unsigned short* V    = (unsigned short*)(ws + 6422528);
    unsigned short* pre  = (unsigned short*)(ws + 32112640);
    unsigned short* WHi  = (unsigned short*)(ws + 38535168);
    unsigned short* WLo  = (unsigned short*)(ws + 38666240);
    unsigned short* Wp   = (unsigned short*)(ws + 38797312);

    kW_prep<<<17, 256, 0, stream>>>(Wout, Wk, Wv, qp, WHi, WLo, Wp);
    k1_mfma<<<(BATCH*NPIX)/64, 256, 0, stream>>>(x, Wp, cost, V);
    k2_agg <<<(BATCH*NOPIX)/4, 256, 0, stream>>>(cost, V, ascale, rpb, pre);
    k3_mfma<<<BATCH*28, 256, 0, stream>>>(pre, WHi, WLo, out);
}

// Round 8
// 64.022 us; speedup vs baseline: 1.5031x; 1.5031x over previous
//
#include <hip/hip_runtime.h>
#include <hip/hip_bf16.h>

#define BATCH 16
#define CIN   128
#define HIMG  56
#define WIMG  56
#define NPIX  (HIMG*WIMG)      // 3136
#define CS    256
#define NQ    4
#define HOUT  28
#define WOUT  28
#define NOPIX (HOUT*WOUT)      // 784
#define QSCALE 0.17677669529663687f   // hc^-0.5 = 1/sqrt(32)
#define NCOL  288              // 256 V cols + 32 qk cols

typedef __attribute__((ext_vector_type(8))) short    bf16x8;
typedef __attribute__((ext_vector_type(4))) float    f32x4;
typedef __attribute__((ext_vector_type(4))) unsigned u32x4;

static __device__ __forceinline__ unsigned short f2bf(float f) {
    return __builtin_bit_cast(unsigned short, __float2bfloat16(f));
}
static __device__ __forceinline__ float bf2f(unsigned short u) {
    return __builtin_bit_cast(float, (unsigned)u << 16);
}
static __device__ __forceinline__ unsigned int pack2(float a, float b) {
    return (unsigned)f2bf(a) | ((unsigned)f2bf(b) << 16);
}

// ---------- kernel W: all weight prep, parallel ----------
// blocks 0..7  : Wout -> WoutHi/WoutLo bf16 split (hi + residual)
// blocks 8..15 : W' rows 0..255 (WvT repack, bf16, XOR-swizzled)
// block  16    : W' rows 256..287 (Wq' = q-folded Wk, bf16, XOR-swizzled)
// W' row n = GEMM column n, 256 bytes; k-byte-offset XORed with ((n&7)<<4)
// so k1's B-frag ds_read_b128 is bank-conflict-free (T2).
__global__ __launch_bounds__(256) void kW_prep(
    const float* __restrict__ Wout, const float* __restrict__ Wk,
    const float* __restrict__ Wv,   const float* __restrict__ qp,
    unsigned short* __restrict__ WHi, unsigned short* __restrict__ WLo,
    unsigned short* __restrict__ Wp)
{
    __shared__ float buf[4352];   // 17 KB, aliased per block role
    const int t   = threadIdx.x;
    const int blk = blockIdx.x;
    char* wp = (char*)Wp;

    if (blk < 8) {
        // ---- Wout hi/lo split, coalesced ----
        const size_t base = (size_t)blk * 8192 + t;
        #pragma unroll
        for (int i = 0; i < 32; ++i) {
            const float f = Wout[base + i*256];
            const unsigned short h = f2bf(f);
            WHi[base + i*256] = h;
            WLo[base + i*256] = f2bf(f - bf2f(h));
        }
    } else if (blk < 16) {
        // ---- WvT repack: W' row ch holds Wv[*, ch] as bf16 pairs ----
        float (*lt)[33] = (float(*)[33])buf;           // 128*33 = 4224
        const int ch0 = (blk - 8) * 32;
        const int j = t & 31, r = t >> 5;              // r = 0..7
        #pragma unroll
        for (int pass = 0; pass < 16; ++pass) {
            const int c = r + pass*8;
            lt[c][j] = Wv[(size_t)c*CS + ch0 + j];     // coalesced 128B/row
        }
        __syncthreads();
        const int lch = t >> 3, sub = t & 7;
        const int ch  = ch0 + lch;
        const int mask = (ch & 7) << 4;
        #pragma unroll
        for (int i = 0; i < 8; ++i) {
            const int c2 = sub*8 + i;
            const unsigned u = pack2(lt[2*c2][lch], lt[2*c2+1][lch]);
            *(unsigned*)(wp + ch*256 + ((c2*4) ^ mask)) = u;
        }
    } else {
        // ---- Wq'[qh][c] = sum_j Wk[c][h*32+j] * q[q][h*32+j] * QSCALE ----
        float* qs = buf;                               // 1024 floats
        for (int i = t; i < NQ*CS; i += 256) qs[i] = qp[i] * QSCALE;
        __syncthreads();
        const int qh = t >> 3, kg = t & 7;             // 32 rows x 8 k-groups
        const int h = qh & 7, q = qh >> 3;
        const int row = 256 + qh;
        const int mask = (qh & 7) << 4;                // == (row&7)<<4
        const float* qv = &qs[q*CS + h*32];
        #pragma unroll
        for (int i = 0; i < 8; ++i) {
            const int c2 = kg*8 + i;
            float d0 = 0.f, d1 = 0.f;
            const float* wk0 = Wk + (size_t)(2*c2)*CS + h*32;
            const float* wk1 = wk0 + CS;
            #pragma unroll
            for (int j4 = 0; j4 < 32; j4 += 4) {
                const float4 a0 = *(const float4*)(wk0 + j4);
                const float4 a1 = *(const float4*)(wk1 + j4);
                const float4 qq = *(const float4*)(qv + j4);
                d0 = fmaf(a0.x, qq.x, d0); d0 = fmaf(a0.y, qq.y, d0);
                d0 = fmaf(a0.z, qq.z, d0); d0 = fmaf(a0.w, qq.w, d0);
                d1 = fmaf(a1.x, qq.x, d1); d1 = fmaf(a1.y, qq.y, d1);
                d1 = fmaf(a1.z, qq.z, d1); d1 = fmaf(a1.w, qq.w, d1);
            }
            *(unsigned*)(wp + row*256 + ((c2*4) ^ mask)) = pack2(d0, d1);
        }
    }
}

// ---------- kernel 1: fused transpose+GEMM: x(f32, B,C,N) @ W'(128x288) ----------
// 512 threads / 8 waves / 128 pixels per block. Wp staged once in LDS (73.7 KB,
// pre-swizzled -> conflict-free ds_read_b128); 2 blocks/CU = 4 waves/SIMD.
// A-frags straight from x (16-lane 64B-coalesced dwords, packed to bf16 in regs).
__global__ __launch_bounds__(512, 4) void k1_mfma(
    const float* __restrict__ x, const unsigned short* __restrict__ Wp,
    float* __restrict__ costO, unsigned short* __restrict__ Vout)
{
    __shared__ unsigned short Blds[NCOL*CIN];   // 73728 B

    const int t    = threadIdx.x;               // 0..511
    const int lane = t & 63;
    const int w    = t >> 6;                    // 0..7
    const int l15  = lane & 15;
    const int hi   = lane >> 4;
    const int gp0  = blockIdx.x * 128;          // global pixel base (may cross batch)
    const int gw   = gp0 + w*16;                // wave's 16-pixel row base
    const int b    = gw / NPIX;                 // 16 | NPIX, so wave stays in-batch
    const int p    = gw - b*NPIX + l15;

    // issue A loads (32 dwords, 16-lane coalesced into 64B sectors)
    float av[4][8];
    {
        const float* xb = x + (size_t)b*CIN*NPIX + (size_t)(hi*8)*NPIX + p;
        #pragma unroll
        for (int s = 0; s < 4; ++s)
            #pragma unroll
            for (int j = 0; j < 8; ++j)
                av[s][j] = xb[(size_t)(s*32 + j)*NPIX];
    }

    {   // stage B: linear copy of pre-swizzled image (L2-resident), 9 x 16B/thread
        const bf16x8* src = (const bf16x8*)Wp;
        bf16x8*       dst = (bf16x8*)Blds;
        #pragma unroll
        for (int i = 0; i < 9; ++i)
            dst[t + i*512] = src[t + i*512];
    }

    // pack A to bf16 frags while staging drains
    bf16x8 afr[4];
    #pragma unroll
    for (int s = 0; s < 4; ++s) {
        u32x4 u;
        u[0] = pack2(av[s][0], av[s][1]);
        u[1] = pack2(av[s][2], av[s][3]);
        u[2] = pack2(av[s][4], av[s][5]);
        u[3] = pack2(av[s][6], av[s][7]);
        afr[s] = __builtin_bit_cast(bf16x8, u);
    }
    __syncthreads();

    f32x4 acc[18];
    #pragma unroll
    for (int n = 0; n < 18; ++n) acc[n] = (f32x4){0.f,0.f,0.f,0.f};

    const int   mask  = (l15 & 7) << 4;
    const char* bbase = (const char*)Blds + l15*256;

    #pragma unroll
    for (int s = 0; s < 4; ++s) {
        const char* bs = bbase + ((s*64 + hi*16) ^ mask);
        #pragma unroll
        for (int n = 0; n < 18; ++n) {
            const bf16x8 bfr = *(const bf16x8*)(bs + n*4096);
            acc[n] = __builtin_amdgcn_mfma_f32_16x16x32_bf16(afr[s], bfr, acc[n], 0, 0, 0);
        }
    }

    const size_t prow0 = (size_t)gw + hi*4;
    #pragma unroll
    for (int n = 0; n < 16; ++n) {          // V cols, bf16
        unsigned short* vp = Vout + prow0*CS + n*16 + l15;
        #pragma unroll
        for (int r = 0; r < 4; ++r)
            vp[(size_t)r*CS] = f2bf(acc[n][r]);
    }
    #pragma unroll
    for (int n = 16; n < 18; ++n) {         // qk cols -> cost = exp(qk)
        float* cp = costO + prow0*32 + (n-16)*16 + l15;
        #pragma unroll
        for (int r = 0; r < 4; ++r)
            cp[(size_t)r*32] = __expf(acc[n][r]);
    }
}

// ---------- kernel 2: 9-tap aggregation, 1 wave = 1 output pixel ----------
// XCD-swizzled block order: each XCD's L2 sees a contiguous ~2-batch V slice.
__global__ __launch_bounds__(256) void k2_agg(
    const float* __restrict__ cost, const unsigned short* __restrict__ V,
    const float* __restrict__ ascale, const float* __restrict__ rpb,
    unsigned short* __restrict__ pre)
{
    const int t    = threadIdx.x;
    const int lane = t & 63;
    const int w    = t >> 6;
    // bijective XCD swizzle: 3136 blocks, 3136/8 = 392 contiguous per XCD
    const int bid  = blockIdx.x;
    const int rb   = (bid & 7) * 392 + (bid >> 3);
    const int gp   = rb*4 + w;            // global out-pixel = b*784 + ho*28 + wo
    const int b    = gp / NOPIX;
    const int rem  = gp % NOPIX;
    const int ho   = rem / WOUT, wo = rem % WOUT;
    const int qh   = lane & 31;

    int pk[9];
    #pragma unroll
    for (int k = 0; k < 9; ++k) {
        const int y  = 2*ho - 1 + k/3;
        const int xx = 2*wo - 1 + k%3;
        const bool v = ((unsigned)y < (unsigned)HIMG) && ((unsigned)xx < (unsigned)WIMG);
        pk[k] = v ? (y*WIMG + xx) : -1;
    }

    // per-qh: den and cp[k]
    float cp[9];
    float den = 0.f;
    #pragma unroll
    for (int k = 0; k < 9; ++k) {
        const float s  = (pk[k] >= 0) ? cost[((size_t)(b*NPIX) + pk[k])*32 + qh] : 0.f;
        const float wd = __expf(rpb[k*32 + qh]);
        den   = fmaf(wd, s, den);
        cp[k] = wd * ascale[k*32 + qh] * s;
    }
    const float rden = 1.f / den;

    // coef[k][h] = sum_q cp[k][q*8+h]/den ; broadcast to lane's h = lane>>3
    float coef[9];
    #pragma unroll
    for (int k = 0; k < 9; ++k) {
        float v = cp[k] * rden;
        v += __shfl_xor(v, 8);
        v += __shfl_xor(v, 16);
        coef[k] = __shfl(v, lane >> 3);
    }

    // accumulate 4 channels (lane*4 .. +3)
    float a0 = 0.f, a1 = 0.f, a2 = 0.f, a3 = 0.f;
    #pragma unroll
    for (int k = 0; k < 9; ++k) {
        const int p = (pk[k] >= 0) ? pk[k] : 0;       // coef==0 for invalid taps
        const ushort4 v4 = *(const ushort4*)(V + ((size_t)(b*NPIX) + p)*CS + lane*4);
        a0 = fmaf(coef[k], bf2f(v4.x), a0);
        a1 = fmaf(coef[k], bf2f(v4.y), a1);
        a2 = fmaf(coef[k], bf2f(v4.z), a2);
        a3 = fmaf(coef[k], bf2f(v4.w), a3);
    }
    ushort4 o;
    o.x = f2bf(a0); o.y = f2bf(a1); o.z = f2bf(a2); o.w = f2bf(a3);
    *(ushort4*)(pre + (size_t)gp*CS + lane*4) = o;
}

// ---------- kernel 3: out = Wout @ pre^T via MFMA, hi/lo split A ----------
__global__ __launch_bounds__(256) void k3_mfma(
    const unsigned short* __restrict__ pre, const unsigned short* __restrict__ WHi,
    const unsigned short* __restrict__ WLo, float* __restrict__ out)
{
    const int t    = threadIdx.x;
    const int lane = t & 63;
    const int w    = t >> 6;
    const int l15  = lane & 15;
    const int hi   = lane >> 4;
    const int blk  = blockIdx.x;           // b*28 + otile*7 + ptile
    const int b    = blk / 28;
    const int rem  = blk % 28;
    const int o0   = (rem / 7) * 64 + w * 16;
    const int p0   = (rem % 7) * 112;

    bf16x8 aH[8], aL[8];
    {
        const unsigned short* ah = WHi + (size_t)(o0 + l15)*CS + hi*8;
        const unsigned short* al = WLo + (size_t)(o0 + l15)*CS + hi*8;
        #pragma unroll
        for (int s = 0; s < 8; ++s) {
            aH[s] = *(const bf16x8*)(ah + s*32);
            aL[s] = *(const bf16x8*)(al + s*32);
        }
    }

    const unsigned short* bbase = pre + ((size_t)(b*NOPIX) + p0 + l15)*CS + hi*8;

    f32x4 acc[7];
    #pragma unroll
    for (int n = 0; n < 7; ++n) acc[n] = (f32x4){0.f,0.f,0.f,0.f};

    #pragma unroll
    for (int n = 0; n < 7; ++n) {
        const unsigned short* bn = bbase + (size_t)(n*16)*CS;
        bf16x8 bf[8];
        #pragma unroll
        for (int s = 0; s < 8; ++s) bf[s] = *(const bf16x8*)(bn + s*32);
        #pragma unroll
        for (int s = 0; s < 8; ++s) {
            acc[n] = __builtin_amdgcn_mfma_f32_16x16x32_bf16(aH[s], bf[s], acc[n], 0, 0, 0);
            acc[n] = __builtin_amdgcn_mfma_f32_16x16x32_bf16(aL[s], bf[s], acc[n], 0, 0, 0);
        }
    }

    #pragma unroll
    for (int n = 0; n < 7; ++n) {
        #pragma unroll
        for (int r = 0; r < 4; ++r)
            out[((size_t)(b*CS) + o0 + hi*4 + r)*NOPIX + p0 + n*16 + l15] = acc[n][r];
    }
}

extern "C" void kernel_launch(void* const* d_in, const int* in_sizes, int n_in,
                              void* d_out, int out_size, void* d_ws, size_t ws_size,
                              hipStream_t stream) {
    const float* x      = (const float*)d_in[0];
    const float* Wk     = (const float*)d_in[1];
    const float* Wv     = (const float*)d_in[2];
    const float* Wout   = (const float*)d_in[3];
    const float* qp     = (const float*)d_in[4];
    const float* ascale = (const float*)d_in[5];
    const float* rpb    = (const float*)d_in[6];
    float* out = (float*)d_out;

    // ws layout (bytes):
    //   cost f32 : 6,422,528
    //   V bf16   : 25,690,112
    //   pre bf16 : 6,422,528
    //   WoutHi   : 131,072 | WoutLo: 131,072 | Wp: 73,728   -> ~38.9 MB
    char* ws = (char*)d_ws;
    float*          cost = (float*)(ws);
    unsigned short* V    = (unsigned short*)(ws + 6422528);
    unsigned short* pre  = (unsigned short*)(ws + 32112640);
    unsigned short* WHi  = (unsigned short*)(ws + 38535168);
    unsigned short* WLo  = (unsigned short*)(ws + 38666240);
    unsigned short* Wp   = (unsigned short*)(ws + 38797312);

    kW_prep<<<17, 256, 0, stream>>>(Wout, Wk, Wv, qp, WHi, WLo, Wp);
    k1_mfma<<<(BATCH*NPIX)/128, 512, 0, stream>>>(x, Wp, cost, V);
    k2_agg <<<(BATCH*NOPIX)/4, 256, 0, stream>>>(cost, V, ascale, rpb, pre);
    k3_mfma<<<BATCH*28, 256, 0, stream>>>(pre, WHi, WLo, out);
}

// Round 9
// 62.656 us; speedup vs baseline: 1.5359x; 1.0218x over previous
//
#include <hip/hip_runtime.h>
#include <hip/hip_bf16.h>

#define BATCH 16
#define CIN   128
#define HIMG  56
#define WIMG  56
#define NPIX  (HIMG*WIMG)      // 3136
#define CS    256
#define NQ    4
#define HOUT  28
#define WOUT  28
#define NOPIX (HOUT*WOUT)      // 784
#define QSCALE 0.17677669529663687f   // hc^-0.5 = 1/sqrt(32)
#define NCOL  288              // 256 V cols + 32 qk cols

typedef __attribute__((ext_vector_type(8))) short    bf16x8;
typedef __attribute__((ext_vector_type(4))) float    f32x4;
typedef __attribute__((ext_vector_type(4))) unsigned u32x4;

static __device__ __forceinline__ unsigned short f2bf(float f) {
    return __builtin_bit_cast(unsigned short, __float2bfloat16(f));
}
static __device__ __forceinline__ float bf2f(unsigned short u) {
    return __builtin_bit_cast(float, (unsigned)u << 16);
}
static __device__ __forceinline__ unsigned int pack2(float a, float b) {
    return (unsigned)f2bf(a) | ((unsigned)f2bf(b) << 16);
}

// ---------- kernel W: all weight prep, parallel ----------
// blocks 0..7  : Wout -> WoutHi/WoutLo bf16 split (hi + residual)
// blocks 8..15 : W' rows 0..255 (WvT repack, bf16, XOR-swizzled)
// block  16    : W' rows 256..287 (Wq' = q-folded Wk, bf16, XOR-swizzled)
__global__ __launch_bounds__(256) void kW_prep(
    const float* __restrict__ Wout, const float* __restrict__ Wk,
    const float* __restrict__ Wv,   const float* __restrict__ qp,
    unsigned short* __restrict__ WHi, unsigned short* __restrict__ WLo,
    unsigned short* __restrict__ Wp)
{
    __shared__ float buf[4352];   // 17 KB, aliased per block role
    const int t   = threadIdx.x;
    const int blk = blockIdx.x;
    char* wp = (char*)Wp;

    if (blk < 8) {
        // ---- Wout hi/lo split, coalesced ----
        const size_t base = (size_t)blk * 8192 + t;
        #pragma unroll
        for (int i = 0; i < 32; ++i) {
            const float f = Wout[base + i*256];
            const unsigned short h = f2bf(f);
            WHi[base + i*256] = h;
            WLo[base + i*256] = f2bf(f - bf2f(h));
        }
    } else if (blk < 16) {
        // ---- WvT repack: W' row ch holds Wv[*, ch] as bf16 pairs ----
        float (*lt)[33] = (float(*)[33])buf;           // 128*33 = 4224
        const int ch0 = (blk - 8) * 32;
        const int j = t & 31, r = t >> 5;              // r = 0..7
        #pragma unroll
        for (int pass = 0; pass < 16; ++pass) {
            const int c = r + pass*8;
            lt[c][j] = Wv[(size_t)c*CS + ch0 + j];     // coalesced 128B/row
        }
        __syncthreads();
        const int lch = t >> 3, sub = t & 7;
        const int ch  = ch0 + lch;
        const int mask = (ch & 7) << 4;
        #pragma unroll
        for (int i = 0; i < 8; ++i) {
            const int c2 = sub*8 + i;
            const unsigned u = pack2(lt[2*c2][lch], lt[2*c2+1][lch]);
            *(unsigned*)(wp + ch*256 + ((c2*4) ^ mask)) = u;
        }
    } else {
        // ---- Wq'[qh][c] = sum_j Wk[c][h*32+j] * q[q][h*32+j] * QSCALE ----
        float* qs = buf;                               // 1024 floats
        for (int i = t; i < NQ*CS; i += 256) qs[i] = qp[i] * QSCALE;
        __syncthreads();
        const int qh = t >> 3, kg = t & 7;             // 32 rows x 8 k-groups
        const int h = qh & 7, q = qh >> 3;
        const int row = 256 + qh;
        const int mask = (qh & 7) << 4;                // == (row&7)<<4
        const float* qv = &qs[q*CS + h*32];
        #pragma unroll
        for (int i = 0; i < 8; ++i) {
            const int c2 = kg*8 + i;
            float d0 = 0.f, d1 = 0.f;
            const float* wk0 = Wk + (size_t)(2*c2)*CS + h*32;
            const float* wk1 = wk0 + CS;
            #pragma unroll
            for (int j4 = 0; j4 < 32; j4 += 4) {
                const float4 a0 = *(const float4*)(wk0 + j4);
                const float4 a1 = *(const float4*)(wk1 + j4);
                const float4 qq = *(const float4*)(qv + j4);
                d0 = fmaf(a0.x, qq.x, d0); d0 = fmaf(a0.y, qq.y, d0);
                d0 = fmaf(a0.z, qq.z, d0); d0 = fmaf(a0.w, qq.w, d0);
                d1 = fmaf(a1.x, qq.x, d1); d1 = fmaf(a1.y, qq.y, d1);
                d1 = fmaf(a1.z, qq.z, d1); d1 = fmaf(a1.w, qq.w, d1);
            }
            *(unsigned*)(wp + row*256 + ((c2*4) ^ mask)) = pack2(d0, d1);
        }
    }
}

// ---------- kernel 1: fused transpose+GEMM: x(f32, B,C,N) @ W'(128x288) ----------
// 512 threads / 8 waves / 128 pixels per block. Wp staged once in LDS (73.7 KB,
// pre-swizzled -> conflict-free ds_read_b128); 2 blocks/CU = 4 waves/SIMD.
__global__ __launch_bounds__(512, 4) void k1_mfma(
    const float* __restrict__ x, const unsigned short* __restrict__ Wp,
    float* __restrict__ costO, unsigned short* __restrict__ Vout)
{
    __shared__ unsigned short Blds[NCOL*CIN];   // 73728 B

    const int t    = threadIdx.x;               // 0..511
    const int lane = t & 63;
    const int w    = t >> 6;                    // 0..7
    const int l15  = lane & 15;
    const int hi   = lane >> 4;
    const int gp0  = blockIdx.x * 128;          // global pixel base (may cross batch)
    const int gw   = gp0 + w*16;                // wave's 16-pixel row base
    const int b    = gw / NPIX;                 // 16 | NPIX, so wave stays in-batch
    const int p    = gw - b*NPIX + l15;

    // issue A loads (32 dwords, 16-lane coalesced into 64B sectors)
    float av[4][8];
    {
        const float* xb = x + (size_t)b*CIN*NPIX + (size_t)(hi*8)*NPIX + p;
        #pragma unroll
        for (int s = 0; s < 4; ++s)
            #pragma unroll
            for (int j = 0; j < 8; ++j)
                av[s][j] = xb[(size_t)(s*32 + j)*NPIX];
    }

    {   // stage B: linear copy of pre-swizzled image (L2-resident), 9 x 16B/thread
        const bf16x8* src = (const bf16x8*)Wp;
        bf16x8*       dst = (bf16x8*)Blds;
        #pragma unroll
        for (int i = 0; i < 9; ++i)
            dst[t + i*512] = src[t + i*512];
    }

    // pack A to bf16 frags while staging drains
    bf16x8 afr[4];
    #pragma unroll
    for (int s = 0; s < 4; ++s) {
        u32x4 u;
        u[0] = pack2(av[s][0], av[s][1]);
        u[1] = pack2(av[s][2], av[s][3]);
        u[2] = pack2(av[s][4], av[s][5]);
        u[3] = pack2(av[s][6], av[s][7]);
        afr[s] = __builtin_bit_cast(bf16x8, u);
    }
    __syncthreads();

    f32x4 acc[18];
    #pragma unroll
    for (int n = 0; n < 18; ++n) acc[n] = (f32x4){0.f,0.f,0.f,0.f};

    const int   mask  = (l15 & 7) << 4;
    const char* bbase = (const char*)Blds + l15*256;

    #pragma unroll
    for (int s = 0; s < 4; ++s) {
        const char* bs = bbase + ((s*64 + hi*16) ^ mask);
        #pragma unroll
        for (int n = 0; n < 18; ++n) {
            const bf16x8 bfr = *(const bf16x8*)(bs + n*4096);
            acc[n] = __builtin_amdgcn_mfma_f32_16x16x32_bf16(afr[s], bfr, acc[n], 0, 0, 0);
        }
    }

    const size_t prow0 = (size_t)gw + hi*4;
    #pragma unroll
    for (int n = 0; n < 16; ++n) {          // V cols, bf16
        unsigned short* vp = Vout + prow0*CS + n*16 + l15;
        #pragma unroll
        for (int r = 0; r < 4; ++r)
            vp[(size_t)r*CS] = f2bf(acc[n][r]);
    }
    #pragma unroll
    for (int n = 16; n < 18; ++n) {         // qk cols -> cost = exp(qk)
        float* cp = costO + prow0*32 + (n-16)*16 + l15;
        #pragma unroll
        for (int r = 0; r < 4; ++r)
            cp[(size_t)r*32] = __expf(acc[n][r]);
    }
}

// ---------- kernel 23: fused aggregation + projection ----------
// Block = 32 out-pixels (may cross batch), 512 threads / 8 waves.
// Phase 1: wave w aggregates pixels lp = w*4..w*4+3 (k2 math) -> bf16 pre-tile
//          in LDS, rows 512B, XOR-swizzled by ((row&7)<<4).
// Phase 2: wave w projects o-channels w*32..w*32+31 for all 32 pixels via
//          MFMA with hi/lo-split Wout (A from L2, B from LDS).
__global__ __launch_bounds__(512) void k23_fused(
    const float* __restrict__ cost, const unsigned short* __restrict__ V,
    const float* __restrict__ ascale, const float* __restrict__ rpb,
    const unsigned short* __restrict__ WHi, const unsigned short* __restrict__ WLo,
    float* __restrict__ out)
{
    __shared__ __align__(16) char plds[32*512];   // 16 KB pre-tile

    const int t    = threadIdx.x;
    const int lane = t & 63;
    const int w    = t >> 6;
    // bijective XCD swizzle: 392 blocks, 49 contiguous per XCD (~2 batches' V)
    const int bid  = blockIdx.x;
    const int rb   = (bid & 7) * 49 + (bid >> 3);
    const int gp0  = rb * 32;
    const int qh   = lane & 31;

    // ---- phase 1: aggregate 4 pixels per wave ----
    #pragma unroll
    for (int i = 0; i < 4; ++i) {
        const int lp  = w*4 + i;
        const int gp  = gp0 + lp;
        const int b   = gp / NOPIX;
        const int rem = gp - b*NOPIX;
        const int ho  = rem / WOUT, wo = rem - (rem/WOUT)*WOUT;

        int pk[9];
        #pragma unroll
        for (int k = 0; k < 9; ++k) {
            const int y  = 2*ho - 1 + k/3;
            const int xx = 2*wo - 1 + k%3;
            const bool v = ((unsigned)y < (unsigned)HIMG) && ((unsigned)xx < (unsigned)WIMG);
            pk[k] = v ? (y*WIMG + xx) : -1;
        }

        float cp[9];
        float den = 0.f;
        #pragma unroll
        for (int k = 0; k < 9; ++k) {
            const float s  = (pk[k] >= 0) ? cost[((size_t)(b*NPIX) + pk[k])*32 + qh] : 0.f;
            const float wd = __expf(rpb[k*32 + qh]);
            den   = fmaf(wd, s, den);
            cp[k] = wd * ascale[k*32 + qh] * s;
        }
        const float rden = 1.f / den;

        float coef[9];
        #pragma unroll
        for (int k = 0; k < 9; ++k) {
            float v = cp[k] * rden;
            v += __shfl_xor(v, 8);
            v += __shfl_xor(v, 16);
            coef[k] = __shfl(v, lane >> 3);    // lane's head h = (lane*4)/32 = lane>>3
        }

        float a0 = 0.f, a1 = 0.f, a2 = 0.f, a3 = 0.f;
        #pragma unroll
        for (int k = 0; k < 9; ++k) {
            const int p = (pk[k] >= 0) ? pk[k] : 0;   // coef==0 for invalid taps
            const ushort4 v4 = *(const ushort4*)(V + ((size_t)(b*NPIX) + p)*CS + lane*4);
            a0 = fmaf(coef[k], bf2f(v4.x), a0);
            a1 = fmaf(coef[k], bf2f(v4.y), a1);
            a2 = fmaf(coef[k], bf2f(v4.z), a2);
            a3 = fmaf(coef[k], bf2f(v4.w), a3);
        }
        ushort4 o4;
        o4.x = f2bf(a0); o4.y = f2bf(a1); o4.z = f2bf(a2); o4.w = f2bf(a3);
        // row lp, logical byte lane*8, swizzled (8B store: mask only hits bits 4-6)
        *(ushort4*)(plds + lp*512 + ((lane*8) ^ ((lp & 7) << 4))) = o4;
    }
    __syncthreads();

    // ---- phase 2: project o = w*32 .. w*32+31 for all 32 pixels ----
    const int l15 = lane & 15;
    const int hi  = lane >> 4;
    const int o0  = w * 32;

    // B-frags from LDS: n-group (16 pixels) x kstep s (32 ch = 64B)
    bf16x8 bfr[2][8];
    #pragma unroll
    for (int n = 0; n < 2; ++n) {
        const char* rowb = plds + (n*16 + l15)*512;
        const int   m    = (l15 & 7) << 4;
        #pragma unroll
        for (int s = 0; s < 8; ++s)
            bfr[n][s] = *(const bf16x8*)(rowb + ((s*64 + hi*16) ^ m));
    }

    f32x4 acc[2][2];
    #pragma unroll
    for (int j = 0; j < 2; ++j)
        #pragma unroll
        for (int n = 0; n < 2; ++n) acc[j][n] = (f32x4){0.f,0.f,0.f,0.f};

    #pragma unroll
    for (int j = 0; j < 2; ++j) {
        const unsigned short* ah = WHi + (size_t)(o0 + j*16 + l15)*CS + hi*8;
        const unsigned short* al = WLo + (size_t)(o0 + j*16 + l15)*CS + hi*8;
        #pragma unroll
        for (int s = 0; s < 8; ++s) {
            const bf16x8 aH = *(const bf16x8*)(ah + s*32);
            const bf16x8 aL = *(const bf16x8*)(al + s*32);
            acc[j][0] = __builtin_amdgcn_mfma_f32_16x16x32_bf16(aH, bfr[0][s], acc[j][0], 0, 0, 0);
            acc[j][1] = __builtin_amdgcn_mfma_f32_16x16x32_bf16(aH, bfr[1][s], acc[j][1], 0, 0, 0);
            acc[j][0] = __builtin_amdgcn_mfma_f32_16x16x32_bf16(aL, bfr[0][s], acc[j][0], 0, 0, 0);
            acc[j][1] = __builtin_amdgcn_mfma_f32_16x16x32_bf16(aL, bfr[1][s], acc[j][1], 0, 0, 0);
        }
    }

    // epilogue: D row = o (hi*4+r), col = pixel (l15); per-lane batch math
    #pragma unroll
    for (int n = 0; n < 2; ++n) {
        const int gp  = gp0 + n*16 + l15;
        const int b   = gp / NOPIX;
        const int rem = gp - b*NOPIX;
        float* obase = out + (size_t)b*CS*NOPIX + rem;
        #pragma unroll
        for (int j = 0; j < 2; ++j)
            #pragma unroll
            for (int r = 0; r < 4; ++r)
                obase[(size_t)(o0 + j*16 + hi*4 + r)*NOPIX] = acc[j][n][r];
    }
}

extern "C" void kernel_launch(void* const* d_in, const int* in_sizes, int n_in,
                              void* d_out, int out_size, void* d_ws, size_t ws_size,
                              hipStream_t stream) {
    const float* x      = (const float*)d_in[0];
    const float* Wk     = (const float*)d_in[1];
    const float* Wv     = (const float*)d_in[2];
    const float* Wout   = (const float*)d_in[3];
    const float* qp     = (const float*)d_in[4];
    const float* ascale = (const float*)d_in[5];
    const float* rpb    = (const float*)d_in[6];
    float* out = (float*)d_out;

    // ws layout (bytes):
    //   cost f32 : 6,422,528
    //   V bf16   : 25,690,112
    //   WoutHi   : 131,072 | WoutLo: 131,072 | Wp: 73,728   -> ~32.5 MB
    char* ws = (char*)d_ws;
    float*          cost = (float*)(ws);
    unsigned short* V    = (unsigned short*)(ws + 6422528);
    unsigned short* WHi  = (unsigned short*)(ws + 32112640);
    unsigned short* WLo  = (unsigned short*)(ws + 32243712);
    unsigned short* Wp   = (unsigned short*)(ws + 32374784);

    kW_prep  <<<17, 256, 0, stream>>>(Wout, Wk, Wv, qp, WHi, WLo, Wp);
    k1_mfma  <<<(BATCH*NPIX)/128, 512, 0, stream>>>(x, Wp, cost, V);
    k23_fused<<<(BATCH*NOPIX)/32, 512, 0, stream>>>(cost, V, ascale, rpb, WHi, WLo, out);
}